// Round 2
// baseline (212.484 us; speedup 1.0000x reference)
//
#include <hip/hip_runtime.h>
#include <stdint.h>

typedef unsigned long long u64;

#define N 8192
#define NW 128            // 64-bit words per mask row
#define MAX_OUT 256
#define MASK_BYTES ((size_t)N * NW * 8)   // 8 MiB

// ws layout:
//   [0, 8MB)    mask u64[N][NW]
//     overlap (dead before mask_kernel writes):
//       ws+0      keys    u64[N]   (64 KB)
//       ws+64KB   rank    int[N]   (32 KB)
//       ws+96KB   partial int[32]  (128 B)  per-block valid counts (no zeroing needed)
//   +8MB        order  int[N]     32 KB
//   +32KB       s_s    float[N]   32 KB
//   +64KB       bbox   float4[N] 128 KB
//   +192KB      area   float[N]   32 KB
//   +224KB      nvalid int

// ---------------- Kernel A: build sort keys + zero ranks + per-block valid count ----------------
__global__ __launch_bounds__(256)
void build_keys_kernel(const float* __restrict__ score, u64* __restrict__ keys,
                       int* __restrict__ rank, int* __restrict__ partial) {
    int i = blockIdx.x * 256 + threadIdx.x;
    float s = score[i];
    uint32_t b = __float_as_uint(s);
    keys[i] = ((u64)(~b) << 32) | (uint32_t)i;
    rank[i] = 0;
    int c = (s >= 0.3f) ? 1 : 0;
    for (int off = 32; off; off >>= 1) c += __shfl_down(c, off);
    __shared__ int part[4];
    if ((threadIdx.x & 63) == 0) part[threadIdx.x >> 6] = c;
    __syncthreads();
    if (threadIdx.x == 0) partial[blockIdx.x] = part[0] + part[1] + part[2] + part[3];
}

// ---------------- Kernel B: rank = #{j : key[j] < key[i]}; block(0,0) sums nvalid ----------------
__global__ __launch_bounds__(256)
void rank_kernel(const u64* __restrict__ keys, int* __restrict__ rank,
                 const int* __restrict__ partial, int* __restrict__ nvalid) {
    __shared__ u64 kj[1024];
    const int tid = threadIdx.x;
    if (blockIdx.x == 0 && blockIdx.y == 0 && tid < 64) {
        int v = (tid < 32) ? partial[tid] : 0;
        for (int off = 32; off; off >>= 1) v += __shfl_down(v, off);
        if (tid == 0) *nvalid = v;
    }
    const int jbase = blockIdx.y * 1024;
    for (int t = tid; t < 1024; t += 256) kj[t] = keys[jbase + t];
    __syncthreads();
    const int i = blockIdx.x * 256 + tid;
    const u64 ki = keys[i];
    int c = 0;
    #pragma unroll 8
    for (int j = 0; j < 1024; ++j) c += (kj[j] < ki) ? 1 : 0;
    atomicAdd(&rank[i], c);
}

// ---------------- Kernel C: scatter to sorted order + precompute ----------------
__global__ __launch_bounds__(256)
void scatter_kernel(const float* __restrict__ score, const float* __restrict__ box,
                    const int* __restrict__ rank, int* __restrict__ order,
                    float* __restrict__ s_s, float4* __restrict__ bbox,
                    float* __restrict__ area) {
    int i = blockIdx.x * 256 + threadIdx.x;
    int r = rank[i];
    float s = score[i];
    order[r] = i;
    s_s[r] = s;
    float4 cb = ((const float4*)box)[i * 4];   // box row = 16 f32; first 4 = cx,cy,w,h
    float hw = cb.z * 0.5f, hh = cb.w * 0.5f;
    float x0 = cb.x - hw, y0 = cb.y - hh, x1 = cb.x + hw, y1 = cb.y + hh;
    bbox[r] = make_float4(x0, y0, x1, y1);
    area[r] = (x1 - x0) * (y1 - y0);   // replicate ref: area from xyxy
}

// ---------------- Kernel 2: suppression bitmask (upper triangle) ----------------
__global__ __launch_bounds__(256)
void mask_kernel(const float4* __restrict__ bbox, const float* __restrict__ area,
                 const int* __restrict__ nvalid_p, u64* __restrict__ mask) {
    const int w = blockIdx.x;
    const int i = blockIdx.y * 256 + threadIdx.x;
    __shared__ float4 jb[64];
    __shared__ float  ja[64];
    if (threadIdx.x < 64) {
        jb[threadIdx.x] = bbox[w * 64 + threadIdx.x];
        ja[threadIdx.x] = area[w * 64 + threadIdx.x];
    }
    __syncthreads();
    const int nv = *nvalid_p;
    if (i >= nv) return;
    if (w < (i >> 6)) return;
    float4 a = bbox[i];
    float  aa = area[i];
    u64 bits = 0;
    #pragma unroll 8
    for (int jj = 0; jj < 64; ++jj) {
        float4 b = jb[jj];
        float lx = fmaxf(a.x, b.x), ly = fmaxf(a.y, b.y);
        float rx = fminf(a.z, b.z), ry = fminf(a.w, b.w);
        float ww = fmaxf(rx - lx, 0.0f), hh = fmaxf(ry - ly, 0.0f);
        float inter = ww * hh;
        float denom = ((aa + ja[jj]) - inter) + 1e-9f;  // exact ref op order
        float iou = inter / denom;                       // IEEE div, matches np
        bits |= ((u64)(iou > 0.3f)) << jj;
    }
    mask[(size_t)i * NW + w] = bits;
}

// ---------------- Kernel 3: serial greedy pass — lane-owned remv, no butterfly ----------------
// Lane l owns remv words 2l, 2l+1. Per block b:
//   rw    = 1-stage shfl broadcast of remv word b (kept in blocks <= b-3)
//   rsup  = recent-kept words (b-1 via s1, b-2 via s2), built with |km| parallel
//           shfl broadcasts at the end of the keeping block (no 64-lane reduce)
//   col   = diagonal word (in-block suppression via ballot symmetry)
// Kept rows' full mask rows are OR-merged into lane-owned remv via loads issued
// at the keeping block and consumed 3 blocks later (RA/RB/RC pipes, ~1350 cy
// slack). Lower-triangle garbage words only land in already-consumed remv words.

struct Pipe { u64 col, s1, s2; };
struct Rq   { u64 a0,b0,a1,b1,a2,b2,a3,b3; };

__device__ __forceinline__ u64 bcast64(u64 v, int src) {
    unsigned lo = (unsigned)__shfl((int)(unsigned)v, src);
    unsigned hi = (unsigned)__shfl((int)(unsigned)(v >> 32), src);
    return ((u64)hi << 32) | (u64)lo;
}

__global__ __launch_bounds__(64)
void nms_kernel(const u64* __restrict__ mask, const float* __restrict__ s_s,
                const int* __restrict__ order, const float* __restrict__ box,
                const int* __restrict__ nvalid_p, float* __restrict__ out) {
    const int lane = threadIdx.x;
    const int nv = *nvalid_p;
    const int nblk = (nv + 63) >> 6;
    __shared__ int kpos[MAX_OUT];
    int kcount = 0;
    u64 remv0 = 0, remv1 = 0;   // lane-owned words 2*lane, 2*lane+1
    u64 rsup = 0;               // recent-kept suppression for current block
    u64 carry = 0;              // ... for block after next
    Pipe A = {0,0,0}, B = {0,0,0};
    Rq RA = {0,0,0,0,0,0,0,0}, RB = {0,0,0,0,0,0,0,0}, RC = {0,0,0,0,0,0,0,0};

    // prologue: speculative pipes for blocks 0 and 1
    if (nblk > 0) {
        const u64* r = mask + (size_t)lane * NW;
        A.col = r[0];
        if (nblk > 1) A.s1 = r[1];
        if (nblk > 2) A.s2 = r[2];
    }
    if (nblk > 1) {
        const u64* r = mask + (size_t)(64 + lane) * NW;
        B.col = r[1];
        if (nblk > 2) B.s1 = r[2];
        if (nblk > 3) B.s2 = r[3];
    }

    auto step = [&](int b, Pipe& P, Rq& R) -> bool {
        // 1. merge deferred row-ORs (issued at end of block b-3 into R)
        remv0 |= R.a0 | R.a1 | R.a2 | R.a3;
        remv1 |= R.b0 | R.b1 | R.b2 | R.b3;
        // 2. broadcast remv word b from its owner lane (1 dependent stage)
        u64 sel = (b & 1) ? remv1 : remv0;
        u64 rw = bcast64(sel, b >> 1);
        // 3. consume speculative pipe, reissue for block b+2
        u64 col = P.col, s1v = P.s1, s2v = P.s2;
        const int b2 = b + 2;
        P.col = P.s1 = P.s2 = 0;
        if (b2 < nblk) {
            const u64* r = mask + (size_t)((b2 << 6) + lane) * NW;
            P.col = r[b2];
            if (b2 + 1 < nblk) P.s1 = r[b2 + 1];
            if (b2 + 2 < nblk) P.s2 = r[b2 + 2];
        }
        // 4. resolve
        const int base = b << 6;
        const int rem = nv - base;
        u64 validm = (rem >= 64) ? ~0ull : ((1ull << rem) - 1ull);
        u64 todo = validm & ~rw & ~rsup;
        u64 km = 0;
        while (todo) {
            int l = (int)__builtin_ctzll(todo);
            u64 row_l = __ballot(((col >> l) & 1ull) != 0);  // in-tile row via symmetry
            if (lane == 0) kpos[kcount] = base + l;
            km |= (1ull << l);
            kcount++;
            todo &= ~row_l;
            todo &= ~(1ull << l);
            if (kcount >= MAX_OUT) break;
        }
        // 5. recent-kept suppression words for b+1 / b+2: |km| parallel broadcasts
        u64 add1 = 0, add2 = 0;
        u64 t = km;
        while (t) {
            int l = (int)__builtin_ctzll(t); t &= t - 1;
            add1 |= bcast64(s1v, l);
            add2 |= bcast64(s2v, l);
        }
        rsup  = carry | add1;
        carry = add2;
        // 6. issue deferred full-row loads for this block's kept (consumed at b+3)
        int l0 = -1, l1 = -1, l2 = -1, l3 = -1;
        u64 t2 = km;
        if (t2) { l0 = (int)__builtin_ctzll(t2); t2 &= t2 - 1; }
        if (t2) { l1 = (int)__builtin_ctzll(t2); t2 &= t2 - 1; }
        if (t2) { l2 = (int)__builtin_ctzll(t2); t2 &= t2 - 1; }
        if (t2) { l3 = (int)__builtin_ctzll(t2); t2 &= t2 - 1; }
        R.a0=R.b0=R.a1=R.b1=R.a2=R.b2=R.a3=R.b3 = 0;
        if (l0 >= 0) { const u64* p = mask + (size_t)(base + l0) * NW + 2 * lane; R.a0 = p[0]; R.b0 = p[1]; }
        if (l1 >= 0) { const u64* p = mask + (size_t)(base + l1) * NW + 2 * lane; R.a1 = p[0]; R.b1 = p[1]; }
        if (l2 >= 0) { const u64* p = mask + (size_t)(base + l2) * NW + 2 * lane; R.a2 = p[0]; R.b2 = p[1]; }
        if (l3 >= 0) { const u64* p = mask + (size_t)(base + l3) * NW + 2 * lane; R.a3 = p[0]; R.b3 = p[1]; }
        // rare overflow (>4 kept in one block): synchronous merge, correct but slow
        while (t2) {
            int l = (int)__builtin_ctzll(t2); t2 &= t2 - 1;
            const u64* p = mask + (size_t)(base + l) * NW + 2 * lane;
            remv0 |= p[0]; remv1 |= p[1];
        }
        return kcount < MAX_OUT;
    };

    bool run = true;
    for (int b = 0; run && b < nblk; b += 6) {
        run = step(b, A, RA);
        if (run && b + 1 < nblk) run = step(b + 1, B, RB);
        if (run && b + 2 < nblk) run = step(b + 2, A, RC);
        if (run && b + 3 < nblk) run = step(b + 3, B, RA);
        if (run && b + 4 < nblk) run = step(b + 4, A, RB);
        if (run && b + 5 < nblk) run = step(b + 5, B, RC);
    }

    __syncthreads();
    // outputs: [score 256][box 256*16][valid 256], all float32
    float* out_score = out;
    float* out_box   = out + MAX_OUT;
    float* out_valid = out + MAX_OUT + MAX_OUT * 16;
    const float4* box4 = (const float4*)box;
    float4* ob4 = (float4*)out_box;
    for (int t = lane; t < MAX_OUT; t += 64) {
        if (t < kcount) {
            int p = kpos[t];
            out_score[t] = s_s[p];
            out_valid[t] = 1.0f;
            int oi = order[p];
            #pragma unroll
            for (int q = 0; q < 4; ++q) ob4[t * 4 + q] = box4[oi * 4 + q];
        } else {
            out_score[t] = 0.0f;
            out_valid[t] = 0.0f;
            float4 z = make_float4(0.f, 0.f, 0.f, 0.f);
            #pragma unroll
            for (int q = 0; q < 4; ++q) ob4[t * 4 + q] = z;
        }
    }
}

extern "C" void kernel_launch(void* const* d_in, const int* in_sizes, int n_in,
                              void* d_out, int out_size, void* d_ws, size_t ws_size,
                              hipStream_t stream) {
    const float* score = (const float*)d_in[0];   // (8192,1) f32
    const float* box   = (const float*)d_in[1];   // (8192,16) f32
    char* ws = (char*)d_ws;
    u64*    mask    = (u64*)ws;
    // overlap region (dead before mask_kernel):
    u64*    keys    = (u64*)ws;                    // 64 KB
    int*    rank    = (int*)(ws + 65536);          // 32 KB
    int*    partial = (int*)(ws + 98304);          // 128 B
    // persistent region:
    int*    order  = (int*)   (ws + MASK_BYTES);
    float*  s_s    = (float*) (ws + MASK_BYTES + 32768);
    float4* bbox   = (float4*)(ws + MASK_BYTES + 65536);
    float*  area   = (float*) (ws + MASK_BYTES + 65536 + 131072);
    int*    nvalid = (int*)   (ws + MASK_BYTES + 65536 + 131072 + 32768);

    build_keys_kernel<<<32, 256, 0, stream>>>(score, keys, rank, partial);
    rank_kernel<<<dim3(32, 8), 256, 0, stream>>>(keys, rank, partial, nvalid);
    scatter_kernel<<<32, 256, 0, stream>>>(score, box, rank, order, s_s, bbox, area);
    mask_kernel<<<dim3(128, 32), 256, 0, stream>>>(bbox, area, nvalid, mask);
    nms_kernel<<<1, 64, 0, stream>>>(mask, s_s, order, box, nvalid, (float*)d_out);
}

// Round 3
// 139.067 us; speedup vs baseline: 1.5279x; 1.5279x over previous
//
#include <hip/hip_runtime.h>
#include <stdint.h>

typedef unsigned long long u64;

#define N 8192
#define NW 128            // 64-bit words per mask row
#define MAX_OUT 256
#define MASK_BYTES ((size_t)N * NW * 8)   // 8 MiB

// ws layout:
//   [0, 8MB)    mask u64[N][NW]
//     overlap (dead before mask_kernel writes):
//       ws+0      keys    u64[N]   (64 KB)
//       ws+64KB   rank    int[N]   (32 KB)
//       ws+96KB   partial int[32]  (128 B)  per-block valid counts (no zeroing needed)
//   +8MB        order  int[N]     32 KB
//   +32KB       s_s    float[N]   32 KB
//   +64KB       bbox   float4[N] 128 KB
//   +192KB      area   float[N]   32 KB
//   +224KB      nvalid int

// ---------------- Kernel A: build sort keys + zero ranks + per-block valid count ----------------
__global__ __launch_bounds__(256)
void build_keys_kernel(const float* __restrict__ score, u64* __restrict__ keys,
                       int* __restrict__ rank, int* __restrict__ partial) {
    int i = blockIdx.x * 256 + threadIdx.x;
    float s = score[i];
    uint32_t b = __float_as_uint(s);
    keys[i] = ((u64)(~b) << 32) | (uint32_t)i;
    rank[i] = 0;
    int c = (s >= 0.3f) ? 1 : 0;
    for (int off = 32; off; off >>= 1) c += __shfl_down(c, off);
    __shared__ int part[4];
    if ((threadIdx.x & 63) == 0) part[threadIdx.x >> 6] = c;
    __syncthreads();
    if (threadIdx.x == 0) partial[blockIdx.x] = part[0] + part[1] + part[2] + part[3];
}

// ---------------- Kernel B: rank = #{j : key[j] < key[i]}; block(0,0) sums nvalid ----------------
__global__ __launch_bounds__(256)
void rank_kernel(const u64* __restrict__ keys, int* __restrict__ rank,
                 const int* __restrict__ partial, int* __restrict__ nvalid) {
    __shared__ u64 kj[1024];
    const int tid = threadIdx.x;
    if (blockIdx.x == 0 && blockIdx.y == 0 && tid < 64) {
        int v = (tid < 32) ? partial[tid] : 0;
        for (int off = 32; off; off >>= 1) v += __shfl_down(v, off);
        if (tid == 0) *nvalid = v;
    }
    const int jbase = blockIdx.y * 1024;
    for (int t = tid; t < 1024; t += 256) kj[t] = keys[jbase + t];
    __syncthreads();
    const int i = blockIdx.x * 256 + tid;
    const u64 ki = keys[i];
    int c = 0;
    #pragma unroll 8
    for (int j = 0; j < 1024; ++j) c += (kj[j] < ki) ? 1 : 0;
    atomicAdd(&rank[i], c);
}

// ---------------- Kernel C: scatter to sorted order + precompute ----------------
__global__ __launch_bounds__(256)
void scatter_kernel(const float* __restrict__ score, const float* __restrict__ box,
                    const int* __restrict__ rank, int* __restrict__ order,
                    float* __restrict__ s_s, float4* __restrict__ bbox,
                    float* __restrict__ area) {
    int i = blockIdx.x * 256 + threadIdx.x;
    int r = rank[i];
    float s = score[i];
    order[r] = i;
    s_s[r] = s;
    float4 cb = ((const float4*)box)[i * 4];   // box row = 16 f32; first 4 = cx,cy,w,h
    float hw = cb.z * 0.5f, hh = cb.w * 0.5f;
    float x0 = cb.x - hw, y0 = cb.y - hh, x1 = cb.x + hw, y1 = cb.y + hh;
    bbox[r] = make_float4(x0, y0, x1, y1);
    area[r] = (x1 - x0) * (y1 - y0);   // replicate ref: area from xyxy
}

// ---------------- Kernel 2: suppression bitmask (upper triangle) ----------------
__global__ __launch_bounds__(256)
void mask_kernel(const float4* __restrict__ bbox, const float* __restrict__ area,
                 const int* __restrict__ nvalid_p, u64* __restrict__ mask) {
    const int w = blockIdx.x;
    const int i = blockIdx.y * 256 + threadIdx.x;
    __shared__ float4 jb[64];
    __shared__ float  ja[64];
    if (threadIdx.x < 64) {
        jb[threadIdx.x] = bbox[w * 64 + threadIdx.x];
        ja[threadIdx.x] = area[w * 64 + threadIdx.x];
    }
    __syncthreads();
    const int nv = *nvalid_p;
    if (i >= nv) return;
    if (w < (i >> 6)) return;
    float4 a = bbox[i];
    float  aa = area[i];
    u64 bits = 0;
    #pragma unroll 8
    for (int jj = 0; jj < 64; ++jj) {
        float4 b = jb[jj];
        float lx = fmaxf(a.x, b.x), ly = fmaxf(a.y, b.y);
        float rx = fminf(a.z, b.z), ry = fminf(a.w, b.w);
        float ww = fmaxf(rx - lx, 0.0f), hh = fmaxf(ry - ly, 0.0f);
        float inter = ww * hh;
        float denom = ((aa + ja[jj]) - inter) + 1e-9f;  // exact ref op order
        float iou = inter / denom;                       // IEEE div, matches np
        bits |= ((u64)(iou > 0.3f)) << jj;
    }
    mask[(size_t)i * NW + w] = bits;
}

// ---------------- Kernel 3: serial greedy pass, pipelined, DPP wave-OR ----------------
// R1 structure (proven: loads 2 blocks in flight, gathers for old kept,
// s1/s2 register carry for recent kept), but the 64-lane OR-reduce uses
// DPP row_shr/row_bcast (VALU pipe, ~4cy/op) instead of 6 dependent
// ds_bpermute stages (~120cy each). Result lands in SGPRs → resolve loop
// runs on the scalar unit.

struct Pipe { u64 col, s1, s2, g0, g1, g2, g3; };

__device__ __forceinline__ unsigned or_dpp32(unsigned v) {
    // wave64 OR-reduce; lane 63 ends with OR of all lanes.
    v |= (unsigned)__builtin_amdgcn_update_dpp(0, (int)v, 0x111, 0xf, 0xf, true); // row_shr:1
    v |= (unsigned)__builtin_amdgcn_update_dpp(0, (int)v, 0x112, 0xf, 0xf, true); // row_shr:2
    v |= (unsigned)__builtin_amdgcn_update_dpp(0, (int)v, 0x114, 0xf, 0xf, true); // row_shr:4
    v |= (unsigned)__builtin_amdgcn_update_dpp(0, (int)v, 0x118, 0xf, 0xf, true); // row_shr:8
    v |= (unsigned)__builtin_amdgcn_update_dpp(0, (int)v, 0x142, 0xf, 0xf, true); // row_bcast:15
    v |= (unsigned)__builtin_amdgcn_update_dpp(0, (int)v, 0x143, 0xf, 0xf, true); // row_bcast:31
    return v;
}

__device__ __forceinline__ u64 wave_or64(u64 v) {
    unsigned lo = or_dpp32((unsigned)v);
    unsigned hi = or_dpp32((unsigned)(v >> 32));
    unsigned slo = (unsigned)__builtin_amdgcn_readlane((int)lo, 63);
    unsigned shi = (unsigned)__builtin_amdgcn_readlane((int)hi, 63);
    return ((u64)shi << 32) | (u64)slo;
}

__global__ __launch_bounds__(64)
void nms_kernel(const u64* __restrict__ mask, const float* __restrict__ s_s,
                const int* __restrict__ order, const float* __restrict__ box,
                const int* __restrict__ nvalid_p, float* __restrict__ out) {
    const int lane = threadIdx.x;
    const int nv = *nvalid_p;
    const int nblk = (nv + 63) >> 6;
    __shared__ int kpos[MAX_OUT];
    int kcount = 0;
    u64 s1m = 0, s2m = 0, s2m_old = 0;

    // prologue: fill pipeline sets for blocks 0 (A) and 1 (B)
    Pipe A, B;
    A.col = A.s1 = A.s2 = A.g0 = A.g1 = A.g2 = A.g3 = 0;
    B.col = B.s1 = B.s2 = B.g0 = B.g1 = B.g2 = B.g3 = 0;
    if (nblk > 0) {
        const u64* r = mask + (size_t)lane * NW;
        A.col = r[0];
        if (nblk > 1) A.s1 = r[1];
        if (nblk > 2) A.s2 = r[2];
    }
    if (nblk > 1) {
        const u64* r = mask + (size_t)(64 + lane) * NW;
        B.col = r[1];
        if (nblk > 2) B.s1 = r[2];
        if (nblk > 3) B.s2 = r[3];
    }

    auto step = [&](int b, Pipe& P) -> bool {
        // consume P (compiler inserts the vmcnt wait here), copy to locals
        u64 col = P.col, s1v = P.s1, s2v = P.s2;
        u64 x = P.g0 | P.g1 | P.g2 | P.g3 | s1m | s2m_old;
        // reissue P for block b+2 (before the reduce so loads fly early)
        const int b2 = b + 2;
        P.col = P.s1 = P.s2 = P.g0 = P.g1 = P.g2 = P.g3 = 0;
        if (b2 < nblk) {
            const u64* r = mask + (size_t)((b2 << 6) + lane) * NW;
            P.col = r[b2];                       // diagonal word (upper tri ok)
            if (b2 + 1 < nblk) P.s1 = r[b2 + 1];
            if (b2 + 2 < nblk) P.s2 = r[b2 + 2];
            const int kc = kcount;               // kept set K_{<b} by definition
            if (lane < kc)       P.g0 = mask[(size_t)kpos[lane]       * NW + b2];
            if (lane +  64 < kc) P.g1 = mask[(size_t)kpos[lane +  64] * NW + b2];
            if (lane + 128 < kc) P.g2 = mask[(size_t)kpos[lane + 128] * NW + b2];
            if (lane + 192 < kc) P.g3 = mask[(size_t)kpos[lane + 192] * NW + b2];
        }
        // suppression word for this block: DPP OR across all 64 lanes (VALU)
        u64 rw = wave_or64(x);
        const int base = b << 6;
        const int rem = nv - base;               // >= 1 since b < nblk
        u64 validm = (rem >= 64) ? ~0ull : ((1ull << rem) - 1ull);
        u64 todo = validm & ~rw;
        u64 km = 0;
        while (todo) {
            int l = (int)__builtin_ctzll(todo);
            u64 row_l = __ballot(((col >> l) & 1ull) != 0);  // in-tile row via symmetry
            if (lane == 0) kpos[kcount] = base + l;
            km |= (1ull << l);
            kcount++;
            todo &= ~row_l;
            todo &= ~(1ull << l);
            if (kcount >= MAX_OUT) break;
        }
        // register-only contributions of this block's kept to blocks b+1, b+2
        u64 keepm = ((km >> lane) & 1ull) ? ~0ull : 0ull;
        s2m_old = s2m;
        s2m = s2v & keepm;   // word b+2 contribution
        s1m = s1v & keepm;   // word b+1 contribution
        return kcount < MAX_OUT;
    };

    bool run = true;
    for (int b = 0; run && b < nblk; b += 2) {
        run = step(b, A);
        if (run && b + 1 < nblk) run = step(b + 1, B);
    }

    __syncthreads();
    // outputs: [score 256][box 256*16][valid 256], all float32
    float* out_score = out;
    float* out_box   = out + MAX_OUT;
    float* out_valid = out + MAX_OUT + MAX_OUT * 16;
    const float4* box4 = (const float4*)box;
    float4* ob4 = (float4*)out_box;
    for (int t = lane; t < MAX_OUT; t += 64) {
        if (t < kcount) {
            int p = kpos[t];
            out_score[t] = s_s[p];
            out_valid[t] = 1.0f;
            int oi = order[p];
            #pragma unroll
            for (int q = 0; q < 4; ++q) ob4[t * 4 + q] = box4[oi * 4 + q];
        } else {
            out_score[t] = 0.0f;
            out_valid[t] = 0.0f;
            float4 z = make_float4(0.f, 0.f, 0.f, 0.f);
            #pragma unroll
            for (int q = 0; q < 4; ++q) ob4[t * 4 + q] = z;
        }
    }
}

extern "C" void kernel_launch(void* const* d_in, const int* in_sizes, int n_in,
                              void* d_out, int out_size, void* d_ws, size_t ws_size,
                              hipStream_t stream) {
    const float* score = (const float*)d_in[0];   // (8192,1) f32
    const float* box   = (const float*)d_in[1];   // (8192,16) f32
    char* ws = (char*)d_ws;
    u64*    mask    = (u64*)ws;
    // overlap region (dead before mask_kernel):
    u64*    keys    = (u64*)ws;                    // 64 KB
    int*    rank    = (int*)(ws + 65536);          // 32 KB
    int*    partial = (int*)(ws + 98304);          // 128 B
    // persistent region:
    int*    order  = (int*)   (ws + MASK_BYTES);
    float*  s_s    = (float*) (ws + MASK_BYTES + 32768);
    float4* bbox   = (float4*)(ws + MASK_BYTES + 65536);
    float*  area   = (float*) (ws + MASK_BYTES + 65536 + 131072);
    int*    nvalid = (int*)   (ws + MASK_BYTES + 65536 + 131072 + 32768);

    build_keys_kernel<<<32, 256, 0, stream>>>(score, keys, rank, partial);
    rank_kernel<<<dim3(32, 8), 256, 0, stream>>>(keys, rank, partial, nvalid);
    scatter_kernel<<<32, 256, 0, stream>>>(score, box, rank, order, s_s, bbox, area);
    mask_kernel<<<dim3(128, 32), 256, 0, stream>>>(bbox, area, nvalid, mask);
    nms_kernel<<<1, 64, 0, stream>>>(mask, s_s, order, box, nvalid, (float*)d_out);
}